// Round 1
// baseline (5464.164 us; speedup 1.0000x reference)
//
#include <hip/hip_runtime.h>
#include <cstdint>
#include <cstddef>

#define TPB 256
#define BQ 128      // number of queries (problem-fixed)
#define DK 192      // SIG_DIM
#define KTOP 32
#define SUB 64      // gallery items per sub-tile
#define QS_STRIDE 132
#define GS_STRIDE 68
#define SS_STRIDE 65

#define NEG_INF (-__builtin_huge_valf())

__device__ __forceinline__ bool pri_gt(float s1, int i1, float s2, int i2) {
    // "greater priority": larger score; tie -> smaller gallery index (jax top_k stability)
    return (s1 > s2) || (s1 == s2 && i1 < i2);
}

struct TopK {
    float ls[KTOP];
    int   li[KTOP];
    float minv; int mini; int minp;
    __device__ __forceinline__ void init() {
        #pragma unroll
        for (int j = 0; j < KTOP; ++j) { ls[j] = NEG_INF; li[j] = 0x7fffffff; }
        minv = NEG_INF; mini = 0x7fffffff; minp = 0;
    }
    __device__ __forceinline__ void insert(float s, int i) {
        if (!pri_gt(s, i, minv, mini)) return;
        #pragma unroll
        for (int j = 0; j < KTOP; ++j) {
            if (j == minp) { ls[j] = s; li[j] = i; }   // static idx -> cndmask, stays in regs
        }
        float mv = ls[0]; int mi = li[0]; int mp = 0;
        #pragma unroll
        for (int j = 1; j < KTOP; ++j) {
            bool lower = (ls[j] < mv) || (ls[j] == mv && li[j] > mi);
            if (lower) { mv = ls[j]; mi = li[j]; mp = j; }
        }
        minv = mv; mini = mi; minp = mp;
    }
};

// ---------------------------------------------------------------------------
// Kernel 1: per-chunk scores (fp32 GEMM tile) + per-chunk top-32 per query.
// Block handles all 128 queries x (nsub*64) gallery items.
// ---------------------------------------------------------------------------
__global__ __launch_bounds__(TPB) void score_chunk_topk(
    const float* __restrict__ Q, const float* __restrict__ G,
    const int* __restrict__ mask,
    float* __restrict__ ws_s, int* __restrict__ ws_i,
    int Ntot, int nsub)
{
    __shared__ float Qs[16 * QS_STRIDE];      // k-major transposed Q slab
    __shared__ float Gs[16 * GS_STRIDE];      // k-major transposed G slab
    __shared__ float Ss[BQ * SS_STRIDE];      // score sub-tile [128][64] (stride 65)

    const int t = threadIdx.x;
    const int chunk = blockIdx.x;
    const int cbase = chunk * nsub * SUB;

    const int q0 = (t >> 4) * 8;              // micro-tile: 8 queries
    const int i0 = (t & 15) * 4;              // x 4 items

    const int selq = t & 127;                 // selection mapping: 2 threads / query
    const int selh = t >> 7;

    TopK tk; tk.init();

    for (int nt = 0; nt < nsub; ++nt) {
        const int g0 = cbase + nt * SUB;
        float acc[8][4];
        #pragma unroll
        for (int r = 0; r < 8; ++r)
            #pragma unroll
            for (int c = 0; c < 4; ++c) acc[r][c] = 0.f;

        for (int kk = 0; kk < DK; kk += 16) {
            __syncthreads();
            {   // stage Q: 128 rows x 16 cols, transposed into Qs[k][q]
                const int q  = t >> 1;
                const int c8 = (t & 1) * 8;
                const float* src = Q + q * DK + kk + c8;
                float4 a = *reinterpret_cast<const float4*>(src);
                float4 b = *reinterpret_cast<const float4*>(src + 4);
                Qs[(c8 + 0) * QS_STRIDE + q] = a.x;
                Qs[(c8 + 1) * QS_STRIDE + q] = a.y;
                Qs[(c8 + 2) * QS_STRIDE + q] = a.z;
                Qs[(c8 + 3) * QS_STRIDE + q] = a.w;
                Qs[(c8 + 4) * QS_STRIDE + q] = b.x;
                Qs[(c8 + 5) * QS_STRIDE + q] = b.y;
                Qs[(c8 + 6) * QS_STRIDE + q] = b.z;
                Qs[(c8 + 7) * QS_STRIDE + q] = b.w;
            }
            {   // stage G: 64 rows x 16 cols, transposed into Gs[k][i]
                const int r  = t >> 2;
                const int c4 = (t & 3) * 4;
                const int g  = g0 + r;
                float4 a = make_float4(0.f, 0.f, 0.f, 0.f);
                if (g < Ntot)
                    a = *reinterpret_cast<const float4*>(G + (size_t)g * DK + kk + c4);
                Gs[(c4 + 0) * GS_STRIDE + r] = a.x;
                Gs[(c4 + 1) * GS_STRIDE + r] = a.y;
                Gs[(c4 + 2) * GS_STRIDE + r] = a.z;
                Gs[(c4 + 3) * GS_STRIDE + r] = a.w;
            }
            __syncthreads();
            #pragma unroll
            for (int k = 0; k < 16; ++k) {
                float4 qa = *reinterpret_cast<const float4*>(&Qs[k * QS_STRIDE + q0]);
                float4 qb = *reinterpret_cast<const float4*>(&Qs[k * QS_STRIDE + q0 + 4]);
                float4 gv = *reinterpret_cast<const float4*>(&Gs[k * GS_STRIDE + i0]);
                float qr[8] = {qa.x, qa.y, qa.z, qa.w, qb.x, qb.y, qb.z, qb.w};
                float gr[4] = {gv.x, gv.y, gv.z, gv.w};
                #pragma unroll
                for (int r = 0; r < 8; ++r)
                    #pragma unroll
                    for (int c = 0; c < 4; ++c)
                        acc[r][c] = fmaf(qr[r], gr[c], acc[r][c]);
            }
        }
        __syncthreads();
        #pragma unroll
        for (int r = 0; r < 8; ++r)
            #pragma unroll
            for (int c = 0; c < 4; ++c)
                Ss[(q0 + r) * SS_STRIDE + i0 + c] = acc[r][c];
        __syncthreads();
        {   // selection: thread (selq, selh) scans 32 items of this sub-tile
            const int ibase = selh * 32;
            const int gbase = g0 + ibase;
            const size_t mrow = (size_t)selq * (size_t)Ntot;
            for (int i = 0; i < 32; ++i) {
                const int g = gbase + i;
                if (g >= Ntot) break;
                float s = Ss[selq * SS_STRIDE + ibase + i];
                if (mask[mrow + g]) continue;          // excluded
                tk.insert(s, g);
            }
        }
    }

    // merge the two per-query halves via LDS, write per-chunk top-32 to ws
    __syncthreads();
    if (selh == 1) {
        #pragma unroll
        for (int j = 0; j < KTOP; ++j) {
            Ss[selq * KTOP + j] = tk.ls[j];
            reinterpret_cast<int*>(Ss)[BQ * KTOP + selq * KTOP + j] = tk.li[j];
        }
    }
    __syncthreads();
    if (selh == 0) {
        #pragma unroll
        for (int j = 0; j < KTOP; ++j) {
            float s = Ss[selq * KTOP + j];
            int   i = reinterpret_cast<int*>(Ss)[BQ * KTOP + selq * KTOP + j];
            if (s != NEG_INF) tk.insert(s, i);
        }
        float* wss = ws_s + ((size_t)chunk * BQ + selq) * KTOP;
        int*   wsi = ws_i + ((size_t)chunk * BQ + selq) * KTOP;
        #pragma unroll
        for (int j = 0; j < KTOP; ++j) { wss[j] = tk.ls[j]; wsi[j] = tk.li[j]; }
    }
}

// ---------------------------------------------------------------------------
// Kernel 2: per-query merge of all chunk candidates -> final sorted top-32.
// out layout (float32): [0 .. B*K)   = indices (as float)
//                       [B*K .. 2BK) = scores
// ---------------------------------------------------------------------------
__global__ __launch_bounds__(128) void merge_final(
    const float* __restrict__ ws_s, const int* __restrict__ ws_i,
    float* __restrict__ out, int C, int outB)
{
    __shared__ float lsc[128 * KTOP];
    __shared__ int   lid[128 * KTOP];
    __shared__ float rs[128];
    __shared__ int   ri[128];
    __shared__ int   rt[128];

    const int q = blockIdx.x;
    const int t = threadIdx.x;
    const int total = C * KTOP;

    TopK tk; tk.init();
    for (int c = t; c < total; c += 128) {
        const int ch = c >> 5, j = c & 31;
        const size_t off = ((size_t)ch * BQ + q) * KTOP + j;
        float s = ws_s[off];
        if (s == NEG_INF) continue;
        tk.insert(s, ws_i[off]);
    }
    #pragma unroll
    for (int j = 0; j < KTOP; ++j) { lsc[t * KTOP + j] = tk.ls[j]; lid[t * KTOP + j] = tk.li[j]; }
    __syncthreads();

    unsigned used = 0u;
    for (int round = 0; round < KTOP; ++round) {
        float bs = NEG_INF; int bi = 0x7fffffff; int bp = 0; bool have = false;
        #pragma unroll
        for (int j = 0; j < KTOP; ++j) {
            if (!((used >> j) & 1u)) {
                float s = lsc[t * KTOP + j]; int i = lid[t * KTOP + j];
                if (!have || pri_gt(s, i, bs, bi)) { bs = s; bi = i; bp = j; have = true; }
            }
        }
        rs[t] = bs; ri[t] = bi; rt[t] = t;
        __syncthreads();
        for (int off = 64; off > 0; off >>= 1) {
            if (t < off) {
                if (pri_gt(rs[t + off], ri[t + off], rs[t], ri[t])) {
                    rs[t] = rs[t + off]; ri[t] = ri[t + off]; rt[t] = rt[t + off];
                }
            }
            __syncthreads();
        }
        if (t == rt[0]) used |= (1u << bp);
        if (t == 0) {
            out[q * KTOP + round]                         = (float)ri[0];
            out[(size_t)outB * KTOP + q * KTOP + round]   = rs[0];
        }
        __syncthreads();
    }
}

// ---------------------------------------------------------------------------
extern "C" void kernel_launch(void* const* d_in, const int* in_sizes, int n_in,
                              void* d_out, int out_size, void* d_ws, size_t ws_size,
                              hipStream_t stream)
{
    const float* Q    = (const float*)d_in[0];
    const float* G    = (const float*)d_in[1];
    const int*   mask = (const int*)d_in[2];
    const int B    = in_sizes[0] / DK;   // 128
    const int Ntot = in_sizes[1] / DK;   // 200000

    // choose chunk size so ws fits: need C * B * 32 * 8 bytes
    int nsub = 4;  // nc = 256 -> C = 782 blocks (best balance on 256 CUs)
    long long C;
    for (;;) {
        const int nc = nsub * SUB;
        C = ((long long)Ntot + nc - 1) / nc;
        const size_t need = (size_t)C * (size_t)B * KTOP * 8;
        if (need <= ws_size || nsub >= 1024) break;
        nsub *= 2;
    }
    {
        const int nc = nsub * SUB;
        C = ((long long)Ntot + nc - 1) / nc;
    }
    float* ws_s = (float*)d_ws;
    int*   ws_i = (int*)((char*)d_ws + (size_t)C * (size_t)B * KTOP * sizeof(float));

    score_chunk_topk<<<dim3((unsigned)C), dim3(TPB), 0, stream>>>(
        Q, G, mask, ws_s, ws_i, Ntot, nsub);
    merge_final<<<dim3((unsigned)B), dim3(128), 0, stream>>>(
        ws_s, ws_i, (float*)d_out, (int)C, B);
}

// Round 2
// 2535.253 us; speedup vs baseline: 2.1553x; 2.1553x over previous
//
#include <hip/hip_runtime.h>
#include <cstdint>
#include <cstddef>

#define TPB 256
#define BQ 128      // number of queries (problem-fixed)
#define DK 192      // SIG_DIM
#define KTOP 32
#define SUB 64      // gallery items per sub-tile
#define NSUB 4      // sub-tiles per chunk -> 256 items/chunk
#define QS_STRIDE 132
#define GS_STRIDE 68
#define SS_STRIDE 68   // 4-aligned; XOR column swizzle breaks read conflicts
#define TS_STRIDE 33
#define MAXCH 13       // ceil(782 chunks / 64 lanes)

#define NEG_INF (-__builtin_huge_valf())

// ---------------------------------------------------------------------------
// Kernel 1: fp32 GEMM tile (all 128 queries x 256-item chunk) + mask fold in
// epilogue + per-query sorted top-32 kept in LDS (owner thread per query).
// No per-thread top-k arrays -> no scratch spills.
// ---------------------------------------------------------------------------
__global__ __launch_bounds__(TPB) void score_chunk_topk(
    const float* __restrict__ Q, const float* __restrict__ G,
    const int* __restrict__ mask,
    float* __restrict__ ws_s, int* __restrict__ ws_i,
    int Ntot, int nsub)
{
    __shared__ float Qs[16 * QS_STRIDE];   // k-major transposed Q slab
    __shared__ float Gs[16 * GS_STRIDE];   // k-major transposed G slab
    __shared__ float Ss[BQ * SS_STRIDE];   // masked score sub-tile (swizzled cols)
    __shared__ float topS[BQ * TS_STRIDE]; // per-query sorted desc scores
    __shared__ int   topI[BQ * KTOP];      // matching gallery indices

    const int t = threadIdx.x;
    const int chunk = blockIdx.x;
    const int cbase = chunk * nsub * SUB;

    const int q0 = (t >> 4) * 8;           // micro-tile: 8 queries x 4 items
    const int i0 = (t & 15) * 4;

    for (int e = t; e < BQ * TS_STRIDE; e += TPB) topS[e] = NEG_INF;
    for (int e = t; e < BQ * KTOP; e += TPB)      topI[e] = 0x7fffffff;
    float curMin = NEG_INF;                // valid for owner threads t < 128
    const bool vec_ok = ((Ntot & 3) == 0);

    for (int nt = 0; nt < nsub; ++nt) {
        const int g0 = cbase + nt * SUB;
        float acc[8][4];
        #pragma unroll
        for (int r = 0; r < 8; ++r)
            #pragma unroll
            for (int c = 0; c < 4; ++c) acc[r][c] = 0.f;

        for (int kk = 0; kk < DK; kk += 16) {
            __syncthreads();
            {   // stage Q slab: 128 q x 16 k, transposed
                const int q  = t >> 1;
                const int c8 = (t & 1) * 8;
                const float* src = Q + q * DK + kk + c8;
                float4 a = *reinterpret_cast<const float4*>(src);
                float4 b = *reinterpret_cast<const float4*>(src + 4);
                Qs[(c8 + 0) * QS_STRIDE + q] = a.x;
                Qs[(c8 + 1) * QS_STRIDE + q] = a.y;
                Qs[(c8 + 2) * QS_STRIDE + q] = a.z;
                Qs[(c8 + 3) * QS_STRIDE + q] = a.w;
                Qs[(c8 + 4) * QS_STRIDE + q] = b.x;
                Qs[(c8 + 5) * QS_STRIDE + q] = b.y;
                Qs[(c8 + 6) * QS_STRIDE + q] = b.z;
                Qs[(c8 + 7) * QS_STRIDE + q] = b.w;
            }
            {   // stage G slab: 64 items x 16 k, transposed
                const int r  = t >> 2;
                const int c4 = (t & 3) * 4;
                const int g  = g0 + r;
                float4 a = make_float4(0.f, 0.f, 0.f, 0.f);
                if (g < Ntot)
                    a = *reinterpret_cast<const float4*>(G + (size_t)g * DK + kk + c4);
                Gs[(c4 + 0) * GS_STRIDE + r] = a.x;
                Gs[(c4 + 1) * GS_STRIDE + r] = a.y;
                Gs[(c4 + 2) * GS_STRIDE + r] = a.z;
                Gs[(c4 + 3) * GS_STRIDE + r] = a.w;
            }
            __syncthreads();
            #pragma unroll
            for (int k = 0; k < 16; ++k) {
                float4 qa = *reinterpret_cast<const float4*>(&Qs[k * QS_STRIDE + q0]);
                float4 qb = *reinterpret_cast<const float4*>(&Qs[k * QS_STRIDE + q0 + 4]);
                float4 gv = *reinterpret_cast<const float4*>(&Gs[k * GS_STRIDE + i0]);
                float qr[8] = {qa.x, qa.y, qa.z, qa.w, qb.x, qb.y, qb.z, qb.w};
                float gr[4] = {gv.x, gv.y, gv.z, gv.w};
                #pragma unroll
                for (int r = 0; r < 8; ++r)
                    #pragma unroll
                    for (int c = 0; c < 4; ++c)
                        acc[r][c] = fmaf(qr[r], gr[c], acc[r][c]);
            }
        }

        // epilogue: fold exclusion mask (coalesced int4), write swizzled Ss
        {
            const int gi0 = g0 + i0;
            #pragma unroll
            for (int r = 0; r < 8; ++r) {
                const int q = q0 + r;
                const int col = i0 ^ (((q >> 3) & 7) << 2);
                const size_t mbase = (size_t)q * (size_t)Ntot + (size_t)gi0;
                float o0, o1, o2, o3;
                if (vec_ok && gi0 + 4 <= Ntot) {
                    int4 m = *reinterpret_cast<const int4*>(&mask[mbase]);
                    o0 = m.x ? NEG_INF : acc[r][0];
                    o1 = m.y ? NEG_INF : acc[r][1];
                    o2 = m.z ? NEG_INF : acc[r][2];
                    o3 = m.w ? NEG_INF : acc[r][3];
                } else {
                    o0 = (gi0 + 0 < Ntot && !mask[mbase + 0]) ? acc[r][0] : NEG_INF;
                    o1 = (gi0 + 1 < Ntot && !mask[mbase + 1]) ? acc[r][1] : NEG_INF;
                    o2 = (gi0 + 2 < Ntot && !mask[mbase + 2]) ? acc[r][2] : NEG_INF;
                    o3 = (gi0 + 3 < Ntot && !mask[mbase + 3]) ? acc[r][3] : NEG_INF;
                }
                *reinterpret_cast<float4*>(&Ss[q * SS_STRIDE + col]) =
                    make_float4(o0, o1, o2, o3);
            }
        }
        __syncthreads();

        // selection: owner thread per query, sorted-insert into LDS top-32
        if (t < BQ) {
            const int q = t;
            const int sw = ((q >> 3) & 7) << 2;
            const int sbase = q * SS_STRIDE;
            const int tbase = q * TS_STRIDE;
            const int ibase = q * KTOP;
            for (int i = 0; i < SUB; ++i) {
                float s = Ss[sbase + (i ^ sw)];
                if (s > curMin) {
                    int j = KTOP - 1;
                    while (j > 0) {
                        float v = topS[tbase + j - 1];
                        if (v >= s) break;          // strict: equal -> place after (stable)
                        topS[tbase + j] = v;
                        topI[ibase + j] = topI[ibase + j - 1];
                        --j;
                    }
                    topS[tbase + j] = s;
                    topI[ibase + j] = g0 + i;
                    curMin = topS[tbase + KTOP - 1];
                }
            }
        }
        // next iteration's first k-loop barrier separates these reads from restaging
    }

    __syncthreads();
    {   // coalesced sorted candidate-list write
        const size_t obase = (size_t)chunk * (BQ * KTOP);
        for (int e = t; e < BQ * KTOP; e += TPB) {
            const int q = e >> 5, j = e & 31;
            ws_s[obase + e] = topS[q * TS_STRIDE + j];
            ws_i[obase + e] = topI[q * KTOP + j];
        }
    }
}

// ---------------------------------------------------------------------------
// Kernel 2: per-query tournament merge over sorted per-chunk lists.
// One wave per query; each lane owns <=MAXCH chunks with one-ahead prefetch.
// All arrays statically unrolled -> registers, no scratch.
// out layout (float32): [0 .. B*K) = indices (as float); [B*K .. 2BK) = scores
// ---------------------------------------------------------------------------
__global__ __launch_bounds__(64) void merge_final(
    const float* __restrict__ ws_s, const int* __restrict__ ws_i,
    float* __restrict__ out, int C, int outB)
{
    const int q = blockIdx.x;
    const int lane = threadIdx.x;

    float  val[MAXCH], nv[MAXCH];
    int    idx[MAXCH], ni[MAXCH], pos[MAXCH];
    size_t bs[MAXCH];

    #pragma unroll
    for (int k = 0; k < MAXCH; ++k) {
        const int c = lane + (k << 6);
        if (c < C) {
            const size_t b = ((size_t)c * BQ + q) * KTOP;
            bs[k] = b;
            val[k] = ws_s[b];     idx[k] = ws_i[b];
            nv[k]  = ws_s[b + 1]; ni[k]  = ws_i[b + 1];
            pos[k] = 0;
        } else {
            bs[k] = 0;
            val[k] = NEG_INF; idx[k] = 0x7fffffff;
            nv[k]  = NEG_INF; ni[k]  = 0x7fffffff;
            pos[k] = KTOP;
        }
    }

    for (int r = 0; r < KTOP; ++r) {
        float bv = NEG_INF; int bi = 0x7fffffff; int bk = -1;
        #pragma unroll
        for (int k = 0; k < MAXCH; ++k) {
            if (val[k] > bv || (val[k] == bv && idx[k] < bi)) {
                bv = val[k]; bi = idx[k]; bk = k;
            }
        }
        float wv = bv; int wi = bi; int wl = lane;
        #pragma unroll
        for (int off = 32; off > 0; off >>= 1) {
            float ov = __shfl_xor(wv, off);
            int   oi = __shfl_xor(wi, off);
            int   ol = __shfl_xor(wl, off);
            if (ov > wv || (ov == wv && oi < wi)) { wv = ov; wi = oi; wl = ol; }
        }
        if (lane == 0) {
            out[q * KTOP + r]                             = (float)wi;
            out[(size_t)outB * KTOP + q * KTOP + r]       = wv;
        }
        if (lane == wl) {
            #pragma unroll
            for (int k = 0; k < MAXCH; ++k) {
                if (k == bk) {
                    pos[k]++;
                    val[k] = nv[k]; idx[k] = ni[k];
                    const int np = pos[k] + 1;
                    if (np < KTOP) { nv[k] = ws_s[bs[k] + np]; ni[k] = ws_i[bs[k] + np]; }
                    else           { nv[k] = NEG_INF;          ni[k] = 0x7fffffff; }
                }
            }
        }
    }
}

// ---------------------------------------------------------------------------
extern "C" void kernel_launch(void* const* d_in, const int* in_sizes, int n_in,
                              void* d_out, int out_size, void* d_ws, size_t ws_size,
                              hipStream_t stream)
{
    const float* Q    = (const float*)d_in[0];
    const float* G    = (const float*)d_in[1];
    const int*   mask = (const int*)d_in[2];
    const int B    = in_sizes[0] / DK;   // 128
    const int Ntot = in_sizes[1] / DK;   // 200000

    int nsub = NSUB;                     // 256 items/chunk -> C = 782
    long long C;
    for (;;) {
        const int nc = nsub * SUB;
        C = ((long long)Ntot + nc - 1) / nc;
        const size_t need = (size_t)C * (size_t)B * KTOP * 8;
        if ((need <= ws_size && C <= (long long)MAXCH * 64) || nsub >= 1024) break;
        nsub *= 2;
    }
    {
        const int nc = nsub * SUB;
        C = ((long long)Ntot + nc - 1) / nc;
    }
    float* ws_s = (float*)d_ws;
    int*   ws_i = (int*)((char*)d_ws + (size_t)C * (size_t)B * KTOP * sizeof(float));

    score_chunk_topk<<<dim3((unsigned)C), dim3(TPB), 0, stream>>>(
        Q, G, mask, ws_s, ws_i, Ntot, nsub);
    merge_final<<<dim3((unsigned)B), dim3(64), 0, stream>>>(
        ws_s, ws_i, (float*)d_out, (int)C, B);
}

// Round 3
// 1391.110 us; speedup vs baseline: 3.9279x; 1.8225x over previous
//
#include <hip/hip_runtime.h>
#include <cstdint>
#include <cstddef>

#define TPB 256
#define BQ 128      // number of queries (problem-fixed)
#define DK 192      // SIG_DIM
#define KTOP 32
#define SUB 64      // gallery items per sub-tile
#define NSUB 4      // sub-tiles per chunk -> 256 items/chunk
#define QS_STRIDE 132
#define GS_STRIDE 68
#define SST 132     // transposed score tile stride (items major)
#define CD_STRIDE 129

#define NEG_INF (-__builtin_huge_valf())

// Register-resident unsorted top-32 with tracked min position.
// All indexing static after unroll -> stays in VGPRs (no scratch).
struct RTop32 {
    float ls[KTOP];
    int   li[KTOP];
    float minv;
    int   minp;
    __device__ __forceinline__ void init() {
        #pragma unroll
        for (int j = 0; j < KTOP; ++j) { ls[j] = NEG_INF; li[j] = 0x7fffffff; }
        minv = NEG_INF; minp = 0;
    }
    __device__ __forceinline__ void insert(float s, int g) {
        #pragma unroll
        for (int j = 0; j < KTOP; ++j)
            if (j == minp) { ls[j] = s; li[j] = g; }
        float mv = ls[0]; int mp = 0;
        #pragma unroll
        for (int j = 1; j < KTOP; ++j)
            if (ls[j] < mv) { mv = ls[j]; mp = j; }
        minv = mv; minp = mp;
    }
};

__device__ __forceinline__ bool pri_gt(float s1, int i1, float s2, int i2) {
    return (s1 > s2) || (s1 == s2 && i1 < i2);
}

// ---------------------------------------------------------------------------
// Kernel 1: fp32 GEMM tile (128 queries x 256-item chunk) + mask fold +
// per-(query,half) register top-32. Dumps 64 unsorted candidates per
// (query, chunk) to ws, coalesced via LDS transpose staging.
// ---------------------------------------------------------------------------
__global__ __launch_bounds__(TPB, 2) void score_chunk_topk(
    const float* __restrict__ Q, const float* __restrict__ G,
    const int* __restrict__ mask,
    float* __restrict__ ws_s, int* __restrict__ ws_i,
    int Ntot, int nsub)
{
    __shared__ float Qs[16 * QS_STRIDE];   // k-major transposed Q slab
    __shared__ float Gs[16 * GS_STRIDE];   // k-major transposed G slab
    __shared__ float SsT[SUB * SST];       // transposed score tile [item][query]

    const int t = threadIdx.x;
    const int chunk = blockIdx.x;
    const int cbase = chunk * nsub * SUB;

    const int q0 = (t >> 4) * 8;           // micro-tile: 8 queries x 4 items
    const int i0 = (t & 15) * 4;

    const int q = t & 127;                 // selection: 2 threads per query
    const int h = t >> 7;                  // half (items 0..31 / 32..63)

    const bool vec_ok = ((Ntot & 3) == 0);

    RTop32 tk; tk.init();

    for (int nt = 0; nt < nsub; ++nt) {
        const int g0 = cbase + nt * SUB;
        float acc[8][4];
        #pragma unroll
        for (int r = 0; r < 8; ++r)
            #pragma unroll
            for (int c = 0; c < 4; ++c) acc[r][c] = 0.f;

        for (int kk = 0; kk < DK; kk += 16) {
            __syncthreads();
            {   // stage Q slab: 128 q x 16 k, transposed
                const int qr = t >> 1;
                const int c8 = (t & 1) * 8;
                const float* src = Q + qr * DK + kk + c8;
                float4 a = *reinterpret_cast<const float4*>(src);
                float4 b = *reinterpret_cast<const float4*>(src + 4);
                Qs[(c8 + 0) * QS_STRIDE + qr] = a.x;
                Qs[(c8 + 1) * QS_STRIDE + qr] = a.y;
                Qs[(c8 + 2) * QS_STRIDE + qr] = a.z;
                Qs[(c8 + 3) * QS_STRIDE + qr] = a.w;
                Qs[(c8 + 4) * QS_STRIDE + qr] = b.x;
                Qs[(c8 + 5) * QS_STRIDE + qr] = b.y;
                Qs[(c8 + 6) * QS_STRIDE + qr] = b.z;
                Qs[(c8 + 7) * QS_STRIDE + qr] = b.w;
            }
            {   // stage G slab: 64 items x 16 k, transposed
                const int r  = t >> 2;
                const int c4 = (t & 3) * 4;
                const int g  = g0 + r;
                float4 a = make_float4(0.f, 0.f, 0.f, 0.f);
                if (g < Ntot)
                    a = *reinterpret_cast<const float4*>(G + (size_t)g * DK + kk + c4);
                Gs[(c4 + 0) * GS_STRIDE + r] = a.x;
                Gs[(c4 + 1) * GS_STRIDE + r] = a.y;
                Gs[(c4 + 2) * GS_STRIDE + r] = a.z;
                Gs[(c4 + 3) * GS_STRIDE + r] = a.w;
            }
            __syncthreads();
            #pragma unroll
            for (int k = 0; k < 16; ++k) {
                float4 qa = *reinterpret_cast<const float4*>(&Qs[k * QS_STRIDE + q0]);
                float4 qb = *reinterpret_cast<const float4*>(&Qs[k * QS_STRIDE + q0 + 4]);
                float4 gv = *reinterpret_cast<const float4*>(&Gs[k * GS_STRIDE + i0]);
                float qr8[8] = {qa.x, qa.y, qa.z, qa.w, qb.x, qb.y, qb.z, qb.w};
                float gr[4] = {gv.x, gv.y, gv.z, gv.w};
                #pragma unroll
                for (int r = 0; r < 8; ++r)
                    #pragma unroll
                    for (int c = 0; c < 4; ++c)
                        acc[r][c] = fmaf(qr8[r], gr[c], acc[r][c]);
            }
        }

        // epilogue: fold exclusion mask, write TRANSPOSED tile (float4, aligned)
        {
            const int gi0 = g0 + i0;
            float m[8][4];
            #pragma unroll
            for (int r = 0; r < 8; ++r) {
                const int qq = q0 + r;
                const size_t mbase = (size_t)qq * (size_t)Ntot + (size_t)gi0;
                if (vec_ok && gi0 + 4 <= Ntot) {
                    int4 mk = *reinterpret_cast<const int4*>(&mask[mbase]);
                    m[r][0] = mk.x ? NEG_INF : acc[r][0];
                    m[r][1] = mk.y ? NEG_INF : acc[r][1];
                    m[r][2] = mk.z ? NEG_INF : acc[r][2];
                    m[r][3] = mk.w ? NEG_INF : acc[r][3];
                } else {
                    m[r][0] = (gi0 + 0 < Ntot && !mask[mbase + 0]) ? acc[r][0] : NEG_INF;
                    m[r][1] = (gi0 + 1 < Ntot && !mask[mbase + 1]) ? acc[r][1] : NEG_INF;
                    m[r][2] = (gi0 + 2 < Ntot && !mask[mbase + 2]) ? acc[r][2] : NEG_INF;
                    m[r][3] = (gi0 + 3 < Ntot && !mask[mbase + 3]) ? acc[r][3] : NEG_INF;
                }
            }
            #pragma unroll
            for (int c = 0; c < 4; ++c) {
                *reinterpret_cast<float4*>(&SsT[(i0 + c) * SST + q0]) =
                    make_float4(m[0][c], m[1][c], m[2][c], m[3][c]);
                *reinterpret_cast<float4*>(&SsT[(i0 + c) * SST + q0 + 4]) =
                    make_float4(m[4][c], m[5][c], m[6][c], m[7][c]);
            }
        }
        __syncthreads();

        // selection: lane-consecutive queries read item rows -> conflict-free
        {
            const int ibase = h * 32;
            #pragma unroll 1
            for (int i = 0; i < 32; ++i) {
                float s = SsT[(ibase + i) * SST + q];
                if (s > tk.minv) tk.insert(s, g0 + ibase + i);
            }
        }
        // SsT not rewritten until after 12 barriers in next subtile -> safe
    }

    // dump 64 candidates per query, transposed through LDS for coalescing
    const size_t C64   = (size_t)gridDim.x * 64;
    const size_t obase = (size_t)chunk * 64;
    float* const SsF = SsT;
    int*   const SsI = reinterpret_cast<int*>(SsT);

    __syncthreads();
    #pragma unroll
    for (int j = 0; j < KTOP; ++j)
        SsF[(h * KTOP + j) * CD_STRIDE + q] = tk.ls[j];
    __syncthreads();
    for (int e = t; e < BQ * 64; e += TPB) {
        const int qq = e >> 6, jj = e & 63;
        ws_s[(size_t)qq * C64 + obase + jj] = SsF[jj * CD_STRIDE + qq];
    }
    __syncthreads();
    #pragma unroll
    for (int j = 0; j < KTOP; ++j)
        SsI[(h * KTOP + j) * CD_STRIDE + q] = tk.li[j];
    __syncthreads();
    for (int e = t; e < BQ * 64; e += TPB) {
        const int qq = e >> 6, jj = e & 63;
        ws_i[(size_t)qq * C64 + obase + jj] = SsI[jj * CD_STRIDE + qq];
    }
}

// ---------------------------------------------------------------------------
// Kernel 2: per-query exact top-32 over C*64 unsorted candidates.
// Per-thread register top-32 over coalesced strided slice, then 32-round
// block tournament. out: [0..B*K) indices (as float); [B*K..2BK) scores.
// ---------------------------------------------------------------------------
__global__ __launch_bounds__(256, 2) void merge_topk(
    const float* __restrict__ ws_s, const int* __restrict__ ws_i,
    float* __restrict__ out, int C, int outB)
{
    __shared__ float rs[256];
    __shared__ int   ri[256];
    __shared__ int   rt[256];

    const int q = blockIdx.x;
    const int t = threadIdx.x;
    const int tot = C * 64;
    const size_t base = (size_t)q * (size_t)tot;

    RTop32 tk; tk.init();
    #pragma unroll 1
    for (int s0 = t; s0 < tot; s0 += 256) {
        float s = ws_s[base + s0];
        if (s > tk.minv) tk.insert(s, ws_i[base + s0]);
    }

    unsigned used = 0u;
    for (int r = 0; r < KTOP; ++r) {
        float bv = NEG_INF; int bi = 0x7fffffff; int bp = -1;
        #pragma unroll
        for (int j = 0; j < KTOP; ++j) {
            bool avail = ((used >> j) & 1u) == 0u;
            bool better = avail && pri_gt(tk.ls[j], tk.li[j], bv, bi);
            if (better) { bv = tk.ls[j]; bi = tk.li[j]; bp = j; }
        }
        rs[t] = bv; ri[t] = bi; rt[t] = t;
        __syncthreads();
        for (int off = 128; off > 0; off >>= 1) {
            if (t < off) {
                if (pri_gt(rs[t + off], ri[t + off], rs[t], ri[t])) {
                    rs[t] = rs[t + off]; ri[t] = ri[t + off]; rt[t] = rt[t + off];
                }
            }
            __syncthreads();
        }
        if (t == rt[0] && bp >= 0) used |= (1u << bp);
        if (t == 0) {
            out[q * KTOP + r]                           = (float)ri[0];
            out[(size_t)outB * KTOP + q * KTOP + r]     = rs[0];
        }
        __syncthreads();
    }
}

// ---------------------------------------------------------------------------
extern "C" void kernel_launch(void* const* d_in, const int* in_sizes, int n_in,
                              void* d_out, int out_size, void* d_ws, size_t ws_size,
                              hipStream_t stream)
{
    const float* Q    = (const float*)d_in[0];
    const float* G    = (const float*)d_in[1];
    const int*   mask = (const int*)d_in[2];
    const int B    = in_sizes[0] / DK;   // 128
    const int Ntot = in_sizes[1] / DK;   // 200000

    int nsub = NSUB;
    long long C;
    for (;;) {
        const int nc = nsub * SUB;
        C = ((long long)Ntot + nc - 1) / nc;
        const size_t need = (size_t)C * (size_t)BQ * 64 * 8;
        if (need <= ws_size || nsub >= 1024) break;
        nsub *= 2;
    }
    {
        const int nc = nsub * SUB;
        C = ((long long)Ntot + nc - 1) / nc;
    }
    float* ws_s = (float*)d_ws;
    int*   ws_i = (int*)((char*)d_ws + (size_t)C * (size_t)BQ * 64 * sizeof(float));

    score_chunk_topk<<<dim3((unsigned)C), dim3(TPB), 0, stream>>>(
        Q, G, mask, ws_s, ws_i, Ntot, nsub);
    merge_topk<<<dim3((unsigned)B), dim3(256), 0, stream>>>(
        ws_s, ws_i, (float*)d_out, (int)C, B);
}

// Round 4
// 1130.955 us; speedup vs baseline: 4.8315x; 1.2300x over previous
//
#include <hip/hip_runtime.h>
#include <cstdint>
#include <cstddef>

#define TPB 256
#define BQ 128      // queries (problem-fixed)
#define DK 192      // SIG_DIM
#define KTOP 32
#define SUB 64      // gallery items per sub-tile
#define NSUB 4      // sub-tiles per chunk -> 256 items/chunk
#define QS_STRIDE 132
#define GS_STRIDE 68
#define NGROUPS 32
#define GROUP_SZ 256          // sample = 8192 items

#define NEG_INF (-__builtin_huge_valf())

__device__ __forceinline__ unsigned fkey(float s) {
    unsigned u = __float_as_uint(s);
    return (u & 0x80000000u) ? ~u : (u | 0x80000000u);   // monotone f32 -> u32
}
__device__ __forceinline__ bool pri_gt(float s1, int i1, float s2, int i2) {
    return (s1 > s2) || (s1 == s2 && i1 < i2);           // jax top_k stability
}

// ---------------------------------------------------------------------------
// Kernel 0: per-query threshold = min of 32 group-maxima over an 8192-item
// sample. Provably <= true 32nd-best (32 distinct items). ~98.5th pctile.
// ---------------------------------------------------------------------------
__global__ __launch_bounds__(256) void sample_thresh(
    const float* __restrict__ Q, const float* __restrict__ G,
    const int* __restrict__ mask, float* __restrict__ thr, int Ntot)
{
    __shared__ float Qrow[DK];
    __shared__ float gmax[NGROUPS];
    const int q = blockIdx.x;
    const int t = threadIdx.x;
    const int w = t >> 6, lane = t & 63;
    if (t < DK) Qrow[t] = Q[q * DK + t];
    __syncthreads();

    for (int gi = 0; gi < 8; ++gi) {
        const int g = w * 8 + gi;
        const int base = g * GROUP_SZ;
        float m = NEG_INF;
        for (int j = 0; j < 4; ++j) {
            const int item = base + j * 64 + lane;
            if (item < Ntot) {
                const float4* gp = reinterpret_cast<const float4*>(G + (size_t)item * DK);
                float s0 = 0.f, s1 = 0.f, s2 = 0.f, s3 = 0.f;
                #pragma unroll 8
                for (int kk = 0; kk < DK / 16; ++kk) {
                    float4 g0 = gp[kk * 4 + 0], g1 = gp[kk * 4 + 1];
                    float4 g2 = gp[kk * 4 + 2], g3 = gp[kk * 4 + 3];
                    float4 q0 = *reinterpret_cast<const float4*>(&Qrow[kk * 16 + 0]);
                    float4 q1 = *reinterpret_cast<const float4*>(&Qrow[kk * 16 + 4]);
                    float4 q2 = *reinterpret_cast<const float4*>(&Qrow[kk * 16 + 8]);
                    float4 q3 = *reinterpret_cast<const float4*>(&Qrow[kk * 16 + 12]);
                    s0 = fmaf(g0.x, q0.x, s0); s0 = fmaf(g0.y, q0.y, s0);
                    s0 = fmaf(g0.z, q0.z, s0); s0 = fmaf(g0.w, q0.w, s0);
                    s1 = fmaf(g1.x, q1.x, s1); s1 = fmaf(g1.y, q1.y, s1);
                    s1 = fmaf(g1.z, q1.z, s1); s1 = fmaf(g1.w, q1.w, s1);
                    s2 = fmaf(g2.x, q2.x, s2); s2 = fmaf(g2.y, q2.y, s2);
                    s2 = fmaf(g2.z, q2.z, s2); s2 = fmaf(g2.w, q2.w, s2);
                    s3 = fmaf(g3.x, q3.x, s3); s3 = fmaf(g3.y, q3.y, s3);
                    s3 = fmaf(g3.z, q3.z, s3); s3 = fmaf(g3.w, q3.w, s3);
                }
                float s = (s0 + s1) + (s2 + s3);
                if (!mask[(size_t)q * Ntot + item]) m = fmaxf(m, s);
            }
        }
        #pragma unroll
        for (int off = 32; off > 0; off >>= 1)
            m = fmaxf(m, __shfl_xor(m, off));
        if (lane == 0) gmax[g] = m;
    }
    __syncthreads();
    if (t < 32) {
        float v = gmax[t];
        #pragma unroll
        for (int off = 16; off > 0; off >>= 1)
            v = fminf(v, __shfl_xor(v, off));
        if (t == 0) thr[q] = v;
    }
}

// ---------------------------------------------------------------------------
// Kernel 1: fp32 GEMM (128 q x 256-item chunk) + threshold filter + rare
// mask probe + atomic append. No top-k state anywhere -> no spills.
// ---------------------------------------------------------------------------
__global__ __launch_bounds__(TPB) void score_filter(
    const float* __restrict__ Q, const float* __restrict__ G,
    const int* __restrict__ mask, const float* __restrict__ thrG,
    int* __restrict__ cnt, float* __restrict__ cs, int* __restrict__ ci,
    int Ntot, int CAP)
{
    __shared__ float Qs[16 * QS_STRIDE];   // k-major transposed Q slab
    __shared__ float Gs[16 * GS_STRIDE];   // k-major transposed G slab

    const int t = threadIdx.x;
    const int chunk = blockIdx.x;
    const int cbase = chunk * (NSUB * SUB);
    const int q0 = (t >> 4) * 8;           // micro-tile: 8 queries x 4 items
    const int i0 = (t & 15) * 4;

    float thr[8];
    #pragma unroll
    for (int r = 0; r < 8; ++r) thr[r] = thrG[q0 + r];

    for (int nt = 0; nt < NSUB; ++nt) {
        const int g0 = cbase + nt * SUB;
        float acc[8][4];
        #pragma unroll
        for (int r = 0; r < 8; ++r)
            #pragma unroll
            for (int c = 0; c < 4; ++c) acc[r][c] = 0.f;

        for (int kk = 0; kk < DK; kk += 16) {
            __syncthreads();
            {   // stage Q slab: 128 q x 16 k, transposed
                const int qr = t >> 1;
                const int c8 = (t & 1) * 8;
                const float* src = Q + qr * DK + kk + c8;
                float4 a = *reinterpret_cast<const float4*>(src);
                float4 b = *reinterpret_cast<const float4*>(src + 4);
                Qs[(c8 + 0) * QS_STRIDE + qr] = a.x;
                Qs[(c8 + 1) * QS_STRIDE + qr] = a.y;
                Qs[(c8 + 2) * QS_STRIDE + qr] = a.z;
                Qs[(c8 + 3) * QS_STRIDE + qr] = a.w;
                Qs[(c8 + 4) * QS_STRIDE + qr] = b.x;
                Qs[(c8 + 5) * QS_STRIDE + qr] = b.y;
                Qs[(c8 + 6) * QS_STRIDE + qr] = b.z;
                Qs[(c8 + 7) * QS_STRIDE + qr] = b.w;
            }
            {   // stage G slab: 64 items x 16 k, transposed
                const int r  = t >> 2;
                const int c4 = (t & 3) * 4;
                const int g  = g0 + r;
                float4 a = make_float4(0.f, 0.f, 0.f, 0.f);
                if (g < Ntot)
                    a = *reinterpret_cast<const float4*>(G + (size_t)g * DK + kk + c4);
                Gs[(c4 + 0) * GS_STRIDE + r] = a.x;
                Gs[(c4 + 1) * GS_STRIDE + r] = a.y;
                Gs[(c4 + 2) * GS_STRIDE + r] = a.z;
                Gs[(c4 + 3) * GS_STRIDE + r] = a.w;
            }
            __syncthreads();
            #pragma unroll
            for (int k = 0; k < 16; ++k) {
                float4 qa = *reinterpret_cast<const float4*>(&Qs[k * QS_STRIDE + q0]);
                float4 qb = *reinterpret_cast<const float4*>(&Qs[k * QS_STRIDE + q0 + 4]);
                float4 gv = *reinterpret_cast<const float4*>(&Gs[k * GS_STRIDE + i0]);
                float qr8[8] = {qa.x, qa.y, qa.z, qa.w, qb.x, qb.y, qb.z, qb.w};
                float gr[4] = {gv.x, gv.y, gv.z, gv.w};
                #pragma unroll
                for (int r = 0; r < 8; ++r)
                    #pragma unroll
                    for (int c = 0; c < 4; ++c)
                        acc[r][c] = fmaf(qr8[r], gr[c], acc[r][c]);
            }
        }

        // epilogue: threshold filter, mask probe only on pass, atomic append
        {
            const int gi0 = g0 + i0;
            #pragma unroll
            for (int r = 0; r < 8; ++r) {
                const int q = q0 + r;
                #pragma unroll
                for (int c = 0; c < 4; ++c) {
                    const int g = gi0 + c;
                    const float s = acc[r][c];
                    if (g < Ntot && s >= thr[r]) {
                        if (!mask[(size_t)q * Ntot + g]) {
                            const int pos = atomicAdd(&cnt[q], 1);
                            if (pos < CAP) {
                                cs[(size_t)q * CAP + pos] = s;
                                ci[(size_t)q * CAP + pos] = g;
                            }
                        }
                    }
                }
            }
        }
    }
}

// ---------------------------------------------------------------------------
// Kernel 2: exact per-query top-32 over the candidate list via 4-pass radix
// select (u32 keys) + collect >= pivot + 32-round tie-breaking tournament.
// out: [0..B*K) = indices (as float); [B*K..2BK) = scores.
// ---------------------------------------------------------------------------
__global__ __launch_bounds__(256) void select_topk(
    const float* __restrict__ cs, const int* __restrict__ ci,
    const int* __restrict__ cnt, float* __restrict__ out, int CAP)
{
    __shared__ int hist[256];
    __shared__ int hscan[256];
    __shared__ float Ls[256];
    __shared__ int   Li[256];
    __shared__ int lcnt;
    __shared__ int bS, gtS;
    __shared__ float wrs[4]; __shared__ int wri[4], wrslot[4];

    const int q = blockIdx.x;
    const int t = threadIdx.x;
    const int n0 = cnt[q];
    const int n = n0 < CAP ? n0 : CAP;
    const size_t base = (size_t)q * CAP;

    unsigned prefix = 0, pmask = 0;
    int kneed = KTOP;

    if (n > KTOP) {
        for (int pass = 0; pass < 4; ++pass) {
            const int shift = 24 - pass * 8;
            hist[t] = 0;
            __syncthreads();
            for (int i = t; i < n; i += 256) {
                unsigned k = fkey(cs[base + i]);
                if ((k & pmask) == prefix)
                    atomicAdd(&hist[(k >> shift) & 255], 1);
            }
            __syncthreads();
            // suffix sums via ping-pong Hillis-Steele (8 steps)
            int* src = hist; int* dst = hscan;
            for (int off = 1; off < 256; off <<= 1) {
                int v = src[t] + ((t + off) < 256 ? src[t + off] : 0);
                __syncthreads();
                dst[t] = v;
                __syncthreads();
                int* tmp = src; src = dst; dst = tmp;
            }
            if (src[t] >= kneed && (t == 255 || src[t + 1] < kneed)) {
                bS = t;
                gtS = (t == 255) ? 0 : src[t + 1];
            }
            __syncthreads();
            const int b = bS;
            kneed -= gtS;
            prefix |= ((unsigned)b) << shift;
            pmask  |= 0xFFu << shift;
            __syncthreads();
        }
    }

    // collect all candidates with key >= pivot (n<=32: pivot=0 -> collect all)
    if (t == 0) lcnt = 0;
    __syncthreads();
    const unsigned T = (n > KTOP) ? prefix : 0u;
    for (int i = t; i < n; i += 256) {
        float s = cs[base + i];
        if (fkey(s) >= T) {
            int p = atomicAdd(&lcnt, 1);
            if (p < 256) { Ls[p] = s; Li[p] = ci[base + i]; }
        }
    }
    __syncthreads();
    const int M = lcnt < 256 ? lcnt : 256;

    const int w = t >> 6, lane = t & 63;
    for (int r = 0; r < KTOP; ++r) {
        float bv = (t < M) ? Ls[t] : NEG_INF;
        int   bi = (t < M) ? Li[t] : 0x7fffffff;
        int   bslot = t;
        #pragma unroll
        for (int off = 32; off > 0; off >>= 1) {
            float ov = __shfl_xor(bv, off);
            int   oi = __shfl_xor(bi, off);
            int   os = __shfl_xor(bslot, off);
            if (pri_gt(ov, oi, bv, bi)) { bv = ov; bi = oi; bslot = os; }
        }
        if (lane == 0) { wrs[w] = bv; wri[w] = bi; wrslot[w] = bslot; }
        __syncthreads();
        if (t == 0) {
            float fv = wrs[0]; int fi = wri[0]; int fs = wrslot[0];
            #pragma unroll
            for (int ww = 1; ww < 4; ++ww)
                if (pri_gt(wrs[ww], wri[ww], fv, fi)) {
                    fv = wrs[ww]; fi = wri[ww]; fs = wrslot[ww];
                }
            out[q * KTOP + r]                       = (float)fi;
            out[(size_t)BQ * KTOP + q * KTOP + r]   = fv;
            Ls[fs] = NEG_INF; Li[fs] = 0x7fffffff;   // invalidate winner
        }
        __syncthreads();
    }
}

// ---------------------------------------------------------------------------
extern "C" void kernel_launch(void* const* d_in, const int* in_sizes, int n_in,
                              void* d_out, int out_size, void* d_ws, size_t ws_size,
                              hipStream_t stream)
{
    const float* Q    = (const float*)d_in[0];
    const float* G    = (const float*)d_in[1];
    const int*   mask = (const int*)d_in[2];
    const int Ntot = in_sizes[1] / DK;   // 200000

    // ws layout: [0,512) counters | [512,1024) thresholds | [4096,...) candidates
    int*   cnt = (int*)d_ws;
    float* thr = (float*)((char*)d_ws + 512);
    const size_t avail = ws_size > 4096 ? ws_size - 4096 : 0;
    size_t capq = avail / ((size_t)BQ * 8);
    int CAP = (int)(capq < 32768 ? capq : 32768);
    if (CAP < 64) CAP = 64;   // degenerate ws guard
    float* cs = (float*)((char*)d_ws + 4096);
    int*   ci = (int*)((char*)d_ws + 4096 + (size_t)BQ * CAP * sizeof(float));

    hipMemsetAsync(d_ws, 0, 512, stream);
    sample_thresh<<<dim3(BQ), dim3(256), 0, stream>>>(Q, G, mask, thr, Ntot);

    const int C = (Ntot + NSUB * SUB - 1) / (NSUB * SUB);
    score_filter<<<dim3(C), dim3(TPB), 0, stream>>>(
        Q, G, mask, thr, cnt, cs, ci, Ntot, CAP);
    select_topk<<<dim3(BQ), dim3(256), 0, stream>>>(
        cs, ci, cnt, (float*)d_out, CAP);
}

// Round 5
// 472.966 us; speedup vs baseline: 11.5530x; 2.3912x over previous
//
#include <hip/hip_runtime.h>
#include <cstdint>
#include <cstddef>

#define TPB 256
#define BQ 128      // queries (problem-fixed)
#define DK 192      // SIG_DIM
#define KTOP 32
#define SUB 64      // gallery items per sub-tile
#define NSUB 4      // sub-tiles per chunk -> 256 items/chunk
#define QS_STRIDE 132
#define GS_STRIDE 68
#define SLOTS 32    // candidate slots per (query, chunk); mean ~6, +10 sigma
#define OCAP 65536  // overflow list capacity (pathological only)
#define SCMAX 128   // sample chunks (= 32768 items)

#define NEG_INF (-__builtin_huge_valf())
#define POS_INF (__builtin_huge_valf())

__device__ __forceinline__ unsigned fkey(float s) {
    unsigned u = __float_as_uint(s);
    return (u & 0x80000000u) ? ~u : (u | 0x80000000u);   // monotone f32 -> u32
}
__device__ __forceinline__ bool pri_gt(float s1, int i1, float s2, int i2) {
    return (s1 > s2) || (s1 == s2 && i1 < i2);           // jax top_k stability
}

// ---------------------------------------------------------------------------
// GEMM over one 256-item chunk x all 128 queries.
// mode 0: per-(q,chunk) masked max -> gmaxws   (sample/threshold pass)
// mode 1: threshold filter -> LDS-counter slotted candidate writes (NO global
//         atomics except pathological overflow)
// ---------------------------------------------------------------------------
__global__ __launch_bounds__(TPB) void gemm_chunk(
    const float* __restrict__ Q, const float* __restrict__ G,
    const int* __restrict__ mask, const float* __restrict__ thrG,
    float* __restrict__ gmaxws,
    int* __restrict__ cnt2, float* __restrict__ cs, int* __restrict__ ci,
    int* __restrict__ ocnt, int* __restrict__ oq, int* __restrict__ og,
    float* __restrict__ os,
    int Ntot, int CBLK, int mode)
{
    __shared__ float Qs[16 * QS_STRIDE];   // k-major transposed Q slab
    __shared__ float Gs[16 * GS_STRIDE];   // k-major transposed G slab
    __shared__ int   lcnt[BQ];             // per-query candidate counter (mode 1)

    const int t = threadIdx.x;
    const int chunk = blockIdx.x;
    const int cbase = chunk * (NSUB * SUB);
    const int q0 = (t >> 4) * 8;           // micro-tile: 8 queries x 4 items
    const int i0 = (t & 15) * 4;
    const bool vec_ok = ((Ntot & 3) == 0);

    if (t < BQ) lcnt[t] = 0;               // covered by first barrier below

    float thr8[8];
    if (mode == 1) {
        #pragma unroll
        for (int r = 0; r < 8; ++r) thr8[r] = thrG[q0 + r];
    }
    float qmax[8];
    #pragma unroll
    for (int r = 0; r < 8; ++r) qmax[r] = NEG_INF;

    for (int nt = 0; nt < NSUB; ++nt) {
        const int g0 = cbase + nt * SUB;
        float acc[8][4];
        #pragma unroll
        for (int r = 0; r < 8; ++r)
            #pragma unroll
            for (int c = 0; c < 4; ++c) acc[r][c] = 0.f;

        for (int kk = 0; kk < DK; kk += 16) {
            __syncthreads();
            {   // stage Q slab: 128 q x 16 k, transposed
                const int qr = t >> 1;
                const int c8 = (t & 1) * 8;
                const float* src = Q + qr * DK + kk + c8;
                float4 a = *reinterpret_cast<const float4*>(src);
                float4 b = *reinterpret_cast<const float4*>(src + 4);
                Qs[(c8 + 0) * QS_STRIDE + qr] = a.x;
                Qs[(c8 + 1) * QS_STRIDE + qr] = a.y;
                Qs[(c8 + 2) * QS_STRIDE + qr] = a.z;
                Qs[(c8 + 3) * QS_STRIDE + qr] = a.w;
                Qs[(c8 + 4) * QS_STRIDE + qr] = b.x;
                Qs[(c8 + 5) * QS_STRIDE + qr] = b.y;
                Qs[(c8 + 6) * QS_STRIDE + qr] = b.z;
                Qs[(c8 + 7) * QS_STRIDE + qr] = b.w;
            }
            {   // stage G slab: 64 items x 16 k, transposed
                const int r  = t >> 2;
                const int c4 = (t & 3) * 4;
                const int g  = g0 + r;
                float4 a = make_float4(0.f, 0.f, 0.f, 0.f);
                if (g < Ntot)
                    a = *reinterpret_cast<const float4*>(G + (size_t)g * DK + kk + c4);
                Gs[(c4 + 0) * GS_STRIDE + r] = a.x;
                Gs[(c4 + 1) * GS_STRIDE + r] = a.y;
                Gs[(c4 + 2) * GS_STRIDE + r] = a.z;
                Gs[(c4 + 3) * GS_STRIDE + r] = a.w;
            }
            __syncthreads();
            #pragma unroll
            for (int k = 0; k < 16; ++k) {
                float4 qa = *reinterpret_cast<const float4*>(&Qs[k * QS_STRIDE + q0]);
                float4 qb = *reinterpret_cast<const float4*>(&Qs[k * QS_STRIDE + q0 + 4]);
                float4 gv = *reinterpret_cast<const float4*>(&Gs[k * GS_STRIDE + i0]);
                float qr8[8] = {qa.x, qa.y, qa.z, qa.w, qb.x, qb.y, qb.z, qb.w};
                float gr[4] = {gv.x, gv.y, gv.z, gv.w};
                #pragma unroll
                for (int r = 0; r < 8; ++r)
                    #pragma unroll
                    for (int c = 0; c < 4; ++c)
                        acc[r][c] = fmaf(qr8[r], gr[c], acc[r][c]);
            }
        }

        const int gi0 = g0 + i0;
        if (mode == 0) {
            // sample epilogue: masked per-query max accumulate
            #pragma unroll
            for (int r = 0; r < 8; ++r) {
                const int q = q0 + r;
                const size_t mbase = (size_t)q * (size_t)Ntot + (size_t)gi0;
                if (vec_ok && gi0 + 4 <= Ntot) {
                    int4 mk = *reinterpret_cast<const int4*>(&mask[mbase]);
                    if (!mk.x) qmax[r] = fmaxf(qmax[r], acc[r][0]);
                    if (!mk.y) qmax[r] = fmaxf(qmax[r], acc[r][1]);
                    if (!mk.z) qmax[r] = fmaxf(qmax[r], acc[r][2]);
                    if (!mk.w) qmax[r] = fmaxf(qmax[r], acc[r][3]);
                } else {
                    #pragma unroll
                    for (int c = 0; c < 4; ++c)
                        if (gi0 + c < Ntot && !mask[mbase + c])
                            qmax[r] = fmaxf(qmax[r], acc[r][c]);
                }
            }
        } else {
            // filter epilogue: threshold, rare mask probe, LDS-slotted append
            #pragma unroll
            for (int r = 0; r < 8; ++r) {
                const int q = q0 + r;
                #pragma unroll
                for (int c = 0; c < 4; ++c) {
                    const int g = gi0 + c;
                    const float s = acc[r][c];
                    if (g < Ntot && s >= thr8[r]) {
                        if (!mask[(size_t)q * Ntot + g]) {
                            const int p = atomicAdd(&lcnt[q], 1);
                            if (p < SLOTS) {
                                const size_t o =
                                    ((size_t)q * CBLK + chunk) * SLOTS + p;
                                cs[o] = s; ci[o] = g;
                            } else {
                                const int op = atomicAdd(ocnt, 1);
                                if (op < OCAP) { oq[op] = q; og[op] = g; os[op] = s; }
                            }
                        }
                    }
                }
            }
        }
    }

    if (mode == 0) {
        // reduce qmax across the 16 item-groups (same q-group): lanes t^{1,2,4,8}
        #pragma unroll
        for (int r = 0; r < 8; ++r) {
            #pragma unroll
            for (int off = 1; off < 16; off <<= 1)
                qmax[r] = fmaxf(qmax[r], __shfl_xor(qmax[r], off));
        }
        if ((t & 15) == 0) {
            #pragma unroll
            for (int r = 0; r < 8; ++r)
                gmaxws[(size_t)(q0 + r) * SCMAX + chunk] = qmax[r];
        }
    } else {
        __syncthreads();
        if (t < BQ) {
            int v = lcnt[t]; if (v > SLOTS) v = SLOTS;
            cnt2[(size_t)t * CBLK + chunk] = v;
        }
    }
}

// ---------------------------------------------------------------------------
// thr[q] = min over 32 groups of (max over SC/32 chunk-maxima).
// Provably <= true masked 32nd-best (32 distinct unmasked witnesses).
// ---------------------------------------------------------------------------
__global__ __launch_bounds__(128) void thresh_reduce(
    const float* __restrict__ gmaxws, float* __restrict__ thr, int SC)
{
    const int q = threadIdx.x;
    float tv;
    if (SC >= 32) {
        const int gsz = SC / 32;
        tv = POS_INF;
        for (int g = 0; g < 32; ++g) {
            float gm = NEG_INF;
            for (int j = 0; j < gsz; ++j)
                gm = fmaxf(gm, gmaxws[(size_t)q * SCMAX + g * gsz + j]);
            tv = fminf(tv, gm);
        }
    } else {
        tv = NEG_INF;
    }
    thr[q] = tv;
}

// ---------------------------------------------------------------------------
// Kernel 2: exact per-query top-32 over slotted candidates (+overflow) via
// 4-pass radix select + collect + tie-breaking tournament.
// out: [0..B*K) = indices (as float); [B*K..2BK) = scores.
// ---------------------------------------------------------------------------
__global__ __launch_bounds__(256) void select_topk(
    const float* __restrict__ cs, const int* __restrict__ ci,
    const int* __restrict__ cnt2,
    const int* __restrict__ ocnt, const int* __restrict__ oq,
    const int* __restrict__ og, const float* __restrict__ os,
    float* __restrict__ out, int CBLK)
{
    __shared__ int   cntRow[1024];
    __shared__ int   hist[256];
    __shared__ int   hscan[256];
    __shared__ float Ls[256];
    __shared__ int   Li[256];
    __shared__ int   lcnt, nTotS, bS, gtS;
    __shared__ float wrs[4]; __shared__ int wri[4], wrslot[4];

    const int q = blockIdx.x;
    const int t = threadIdx.x;
    const size_t qbase = (size_t)q * CBLK * SLOTS;
    const size_t cbase = (size_t)q * CBLK;
    const int CC = CBLK < 1024 ? CBLK : 1024;
    const int novf0 = *ocnt;
    const int novf = novf0 < OCAP ? novf0 : OCAP;
    const int nslots = CBLK * SLOTS;

    for (int i = t; i < CC; i += 256) cntRow[i] = cnt2[cbase + i];
    if (t == 0) nTotS = 0;
    __syncthreads();
    {
        int part = 0;
        for (int i = t; i < CBLK; i += 256)
            part += (i < 1024) ? cntRow[i] : cnt2[cbase + i];
        for (int i = t; i < novf; i += 256)
            if (oq[i] == q) part++;
        atomicAdd(&nTotS, part);
    }
    __syncthreads();
    const int nTot = nTotS;

    unsigned prefix = 0, pmask = 0;
    int kneed = KTOP;

    if (nTot > KTOP) {
        for (int pass = 0; pass < 4; ++pass) {
            const int shift = 24 - pass * 8;
            hist[t] = 0;
            __syncthreads();
            for (int i = t; i < nslots; i += 256) {
                const int b = i >> 5, sl = i & 31;
                const int cb = (b < 1024) ? cntRow[b] : cnt2[cbase + b];
                if (sl < cb) {
                    unsigned k = fkey(cs[qbase + i]);
                    if ((k & pmask) == prefix)
                        atomicAdd(&hist[(k >> shift) & 255], 1);
                }
            }
            for (int i = t; i < novf; i += 256) {
                if (oq[i] == q) {
                    unsigned k = fkey(os[i]);
                    if ((k & pmask) == prefix)
                        atomicAdd(&hist[(k >> shift) & 255], 1);
                }
            }
            __syncthreads();
            int* src = hist; int* dst = hscan;
            for (int off = 1; off < 256; off <<= 1) {
                int v = src[t] + ((t + off) < 256 ? src[t + off] : 0);
                __syncthreads();
                dst[t] = v;
                __syncthreads();
                int* tmp = src; src = dst; dst = tmp;
            }
            if (src[t] >= kneed && (t == 255 || src[t + 1] < kneed)) {
                bS = t;
                gtS = (t == 255) ? 0 : src[t + 1];
            }
            __syncthreads();
            const int b = bS;
            kneed -= gtS;
            prefix |= ((unsigned)b) << shift;
            pmask  |= 0xFFu << shift;
            __syncthreads();
        }
    }

    if (t == 0) lcnt = 0;
    __syncthreads();
    const unsigned T = (nTot > KTOP) ? prefix : 0u;
    for (int i = t; i < nslots; i += 256) {
        const int b = i >> 5, sl = i & 31;
        const int cb = (b < 1024) ? cntRow[b] : cnt2[cbase + b];
        if (sl < cb) {
            float s = cs[qbase + i];
            if (fkey(s) >= T) {
                int p = atomicAdd(&lcnt, 1);
                if (p < 256) { Ls[p] = s; Li[p] = ci[qbase + i]; }
            }
        }
    }
    for (int i = t; i < novf; i += 256) {
        if (oq[i] == q) {
            float s = os[i];
            if (fkey(s) >= T) {
                int p = atomicAdd(&lcnt, 1);
                if (p < 256) { Ls[p] = s; Li[p] = og[i]; }
            }
        }
    }
    __syncthreads();
    const int M = lcnt < 256 ? lcnt : 256;

    const int w = t >> 6, lane = t & 63;
    for (int r = 0; r < KTOP; ++r) {
        float bv = (t < M) ? Ls[t] : NEG_INF;
        int   bi = (t < M) ? Li[t] : 0x7fffffff;
        int   bslot = t;
        #pragma unroll
        for (int off = 32; off > 0; off >>= 1) {
            float ov = __shfl_xor(bv, off);
            int   oi = __shfl_xor(bi, off);
            int   osl = __shfl_xor(bslot, off);
            if (pri_gt(ov, oi, bv, bi)) { bv = ov; bi = oi; bslot = osl; }
        }
        if (lane == 0) { wrs[w] = bv; wri[w] = bi; wrslot[w] = bslot; }
        __syncthreads();
        if (t == 0) {
            float fv = wrs[0]; int fi = wri[0]; int fs = wrslot[0];
            #pragma unroll
            for (int ww = 1; ww < 4; ++ww)
                if (pri_gt(wrs[ww], wri[ww], fv, fi)) {
                    fv = wrs[ww]; fi = wri[ww]; fs = wrslot[ww];
                }
            out[q * KTOP + r]                     = (float)fi;
            out[(size_t)BQ * KTOP + q * KTOP + r] = fv;
            Ls[fs] = NEG_INF; Li[fs] = 0x7fffffff;
        }
        __syncthreads();
    }
}

// ---------------------------------------------------------------------------
extern "C" void kernel_launch(void* const* d_in, const int* in_sizes, int n_in,
                              void* d_out, int out_size, void* d_ws, size_t ws_size,
                              hipStream_t stream)
{
    const float* Q    = (const float*)d_in[0];
    const float* G    = (const float*)d_in[1];
    const int*   mask = (const int*)d_in[2];
    const int Ntot = in_sizes[1] / DK;   // 200000

    const int CBLK = (Ntot + NSUB * SUB - 1) / (NSUB * SUB);   // 782
    const int SC   = CBLK < SCMAX ? CBLK : SCMAX;              // 128 sample chunks

    // ws layout (bytes)
    char* w = (char*)d_ws;
    int*   ocnt   = (int*)(w + 0);                  // [0, 4096) control
    float* thr    = (float*)(w + 4096);             // 512 B
    float* gmaxws = (float*)(w + 8192);             // 128*128*4 = 64 KB
    size_t off    = 8192 + (size_t)BQ * SCMAX * 4;
    int*   cnt2   = (int*)(w + off);                // 128*CBLK*4
    off += (size_t)BQ * CBLK * 4; off = (off + 255) & ~(size_t)255;
    float* cs     = (float*)(w + off);              // 128*CBLK*SLOTS*4
    off += (size_t)BQ * CBLK * SLOTS * 4;
    int*   ci     = (int*)(w + off);
    off += (size_t)BQ * CBLK * SLOTS * 4;
    int*   oqv    = (int*)(w + off);   off += (size_t)OCAP * 4;
    int*   ogv    = (int*)(w + off);   off += (size_t)OCAP * 4;
    float* osv    = (float*)(w + off); off += (size_t)OCAP * 4;

    hipMemsetAsync(w, 0, 4096, stream);
    hipMemsetAsync(cnt2, 0, (size_t)BQ * CBLK * 4, stream);

    // mode 0: sample chunk maxima (first SC*256 items)
    gemm_chunk<<<dim3(SC), dim3(TPB), 0, stream>>>(
        Q, G, mask, thr, gmaxws, cnt2, cs, ci, ocnt, oqv, ogv, osv,
        Ntot, CBLK, 0);
    thresh_reduce<<<dim3(1), dim3(128), 0, stream>>>(gmaxws, thr, SC);
    // mode 1: full filter pass
    gemm_chunk<<<dim3(CBLK), dim3(TPB), 0, stream>>>(
        Q, G, mask, thr, gmaxws, cnt2, cs, ci, ocnt, oqv, ogv, osv,
        Ntot, CBLK, 1);
    select_topk<<<dim3(BQ), dim3(256), 0, stream>>>(
        cs, ci, cnt2, ocnt, oqv, ogv, osv, (float*)d_out, CBLK);
}

// Round 7
// 378.836 us; speedup vs baseline: 14.4236x; 1.2485x over previous
//
#include <hip/hip_runtime.h>
#include <hip/hip_bf16.h>
#include <cstdint>
#include <cstddef>

#define BQ 128        // queries (problem-fixed)
#define DK 192        // SIG_DIM
#define KTOP 32
#define ITEMS 128     // gallery items per chunk
#define SLOTS 8       // candidate slots per (query, chunk)
#define QCAP 4096     // per-block LDS rescore queue
#define OCAP 65536    // global overflow list
#define SCN 256       // sample chunks (= 32768 items)
#define MARGIN 0.02f  // > 2x (trunc-G + rne-Q) dot error bound (~0.012)

#define NEG_INF (-__builtin_huge_valf())
#define POS_INF (__builtin_huge_valf())

typedef short short8v __attribute__((ext_vector_type(8)));
typedef float f32x16  __attribute__((ext_vector_type(16)));

__device__ __forceinline__ unsigned fkey(float s) {
    unsigned u = __float_as_uint(s);
    return (u & 0x80000000u) ? ~u : (u | 0x80000000u);   // monotone f32 -> u32
}
__device__ __forceinline__ bool pri_gt(float s1, int i1, float s2, int i2) {
    return (s1 > s2) || (s1 == s2 && i1 < i2);           // jax top_k stability
}
// pack {bf16_trunc(b) : bf16_trunc(a)} in one v_perm_b32 (high halves)
__device__ __forceinline__ unsigned pk_trunc(float a, float b) {
    return __builtin_amdgcn_perm(__float_as_uint(b), __float_as_uint(a),
                                 0x07060302u);
}
__device__ __forceinline__ unsigned short f2bf_rne(float x) {
    unsigned u = __float_as_uint(x);
    unsigned r = u + 0x7FFFu + ((u >> 16) & 1u);
    return (unsigned short)(r >> 16);
}
__device__ __attribute__((noinline)) float dot192(const float* __restrict__ a,
                                                  const float* __restrict__ b) {
    float s = 0.f;
    #pragma unroll 8
    for (int k = 0; k < DK; ++k) s = fmaf(a[k], b[k], s);
    return s;
}

// ---------------------------------------------------------------------------
// Q fp32 -> bf16 (RNE)
// ---------------------------------------------------------------------------
__global__ __launch_bounds__(256) void qprep(
    const float* __restrict__ Qf, unsigned short* __restrict__ Qb)
{
    const int i = blockIdx.x * 256 + threadIdx.x;   // 24576 elems
    if (i < BQ * DK) Qb[i] = f2bf_rne(Qf[i]);
}

// ---------------------------------------------------------------------------
// MFMA scoring over one 128-item chunk x all 128 queries. No LDS staging,
// no k-loop barriers: G is read fp32 (coalesced), truncated to bf16 in
// registers (v_perm), fed to mfma_f32_32x32x16_bf16.
// mode 0: per-(q,chunk) masked bf16-score max  -> gmax
// mode 1: margin-filter -> LDS queue -> exact fp32 cooperative rescore ->
//         slotted append (LDS counters; global atomics only on overflow)
// ---------------------------------------------------------------------------
__global__ __launch_bounds__(256) void mfma_score(
    const float* __restrict__ Qf, const unsigned short* __restrict__ Qb,
    const float* __restrict__ G, const int* __restrict__ mask,
    const float* __restrict__ thrm,
    float* __restrict__ gmax,
    int* __restrict__ cnt2, float* __restrict__ cs, int* __restrict__ ci,
    int* __restrict__ ocnt, int* __restrict__ oq, int* __restrict__ og,
    float* __restrict__ osv,
    int Ntot, int CBLK, int SC, int mode)
{
    __shared__ float    thrmS[BQ];
    __shared__ unsigned queue[QCAP];
    __shared__ int      lcnt[BQ];
    __shared__ int      qn;

    const int t = threadIdx.x;
    const int w = t >> 6, lane = t & 63;
    const int lo5 = lane & 31, hi = lane >> 5;
    const int chunk = blockIdx.x;
    const int cb = chunk * ITEMS;
    const int qbW = w * 32;

    if (t < BQ) { thrmS[t] = mode ? thrm[t] : 0.f; lcnt[t] = 0; }
    if (t == 0) qn = 0;
    __syncthreads();

    // per-lane streaming pointers
    const unsigned short* ap = Qb + (qbW + lo5) * DK + hi * 8;
    const float* gp[4];
    int gItem[4];
    #pragma unroll
    for (int it = 0; it < 4; ++it) {
        int g = cb + it * 32 + lo5;
        gItem[it] = g;
        int gc = g < Ntot ? g : (Ntot - 1);
        gp[it] = G + (size_t)gc * DK + hi * 8;
    }

    f32x16 acc[4] = {
        {0,0,0,0,0,0,0,0,0,0,0,0,0,0,0,0}, {0,0,0,0,0,0,0,0,0,0,0,0,0,0,0,0},
        {0,0,0,0,0,0,0,0,0,0,0,0,0,0,0,0}, {0,0,0,0,0,0,0,0,0,0,0,0,0,0,0,0}};

    #pragma unroll 2
    for (int step = 0; step < DK / 16; ++step) {
        union { uint4 u4; short8v v; } a;
        a.u4 = *reinterpret_cast<const uint4*>(ap);
        ap += 16;
        #pragma unroll
        for (int it = 0; it < 4; ++it) {
            float4 f0 = *reinterpret_cast<const float4*>(gp[it]);
            float4 f1 = *reinterpret_cast<const float4*>(gp[it] + 4);
            gp[it] += 16;
            union { unsigned u[4]; short8v v; } b;
            b.u[0] = pk_trunc(f0.x, f0.y); b.u[1] = pk_trunc(f0.z, f0.w);
            b.u[2] = pk_trunc(f1.x, f1.y); b.u[3] = pk_trunc(f1.z, f1.w);
            acc[it] = __builtin_amdgcn_mfma_f32_32x32x16_bf16(a.v, b.v, acc[it], 0, 0, 0);
        }
    }

    // C layout (32x32): col(item) = lane&31, row(query) = (j&3)+8*(j>>2)+4*hi
    if (mode == 0) {
        #pragma unroll
        for (int j = 0; j < 16; ++j) {
            const int row = (j & 3) + 8 * (j >> 2) + 4 * hi;
            const int q = qbW + row;
            const size_t mrow = (size_t)q * (size_t)Ntot;
            float m = NEG_INF;
            #pragma unroll
            for (int it = 0; it < 4; ++it) {
                const int g = gItem[it];
                if (g < Ntot && !mask[mrow + g]) m = fmaxf(m, acc[it][j]);
            }
            #pragma unroll
            for (int off = 1; off < 32; off <<= 1)
                m = fmaxf(m, __shfl_xor(m, off));
            if (lo5 == 0) gmax[(size_t)q * SC + chunk] = m;
        }
    } else {
        #pragma unroll
        for (int j = 0; j < 16; ++j) {
            const int row = (j & 3) + 8 * (j >> 2) + 4 * hi;
            const int q = qbW + row;
            const float th = thrmS[q];
            #pragma unroll
            for (int it = 0; it < 4; ++it) {
                const int g = gItem[it];
                const float s = acc[it][j];
                if (g < Ntot && s >= th) {
                    if (!mask[(size_t)q * (size_t)Ntot + g]) {
                        const int p = atomicAdd(&qn, 1);
                        if (p < QCAP) {
                            queue[p] = ((unsigned)q << 18) | (unsigned)g;
                        } else {   // pathological: inline exact rescore
                            float sx = dot192(Qf + q * DK, G + (size_t)g * DK);
                            const int op = atomicAdd(ocnt, 1);
                            if (op < OCAP) { oq[op] = q; og[op] = g; osv[op] = sx; }
                        }
                    }
                }
            }
        }
        __syncthreads();
        const int nq = qn < QCAP ? qn : QCAP;
        for (int c = w; c < nq; c += 4) {          // one wave per candidate
            const unsigned pk = queue[c];
            const int q = pk >> 18, g = pk & 0x3FFFF;
            const float* qr = Qf + q * DK;
            const float* gr = G + (size_t)g * DK;
            const int k0 = lane * 3;
            float part = qr[k0] * gr[k0];
            part = fmaf(qr[k0 + 1], gr[k0 + 1], part);
            part = fmaf(qr[k0 + 2], gr[k0 + 2], part);
            #pragma unroll
            for (int off = 32; off > 0; off >>= 1)
                part += __shfl_xor(part, off);
            if (lane == 0) {
                const int p = atomicAdd(&lcnt[q], 1);
                if (p < SLOTS) {
                    const size_t o = ((size_t)q * CBLK + chunk) * SLOTS + p;
                    cs[o] = part; ci[o] = g;
                } else {
                    const int op = atomicAdd(ocnt, 1);
                    if (op < OCAP) { oq[op] = q; og[op] = g; osv[op] = part; }
                }
            }
        }
        __syncthreads();
        if (t < BQ) {
            int v = lcnt[t]; if (v > SLOTS) v = SLOTS;
            cnt2[(size_t)t * CBLK + chunk] = v;
        }
    }
}

// ---------------------------------------------------------------------------
// thrm[q] = (min over 32 groups of group-max of sampled bf16 scores) - MARGIN
// ---------------------------------------------------------------------------
__global__ __launch_bounds__(128) void thresh_reduce(
    const float* __restrict__ gmax, float* __restrict__ thrm, int SC)
{
    const int q = threadIdx.x;
    const int gsz = SC / 32;
    float tv = POS_INF;
    for (int g = 0; g < 32; ++g) {
        float gm = NEG_INF;
        for (int j = 0; j < gsz; ++j)
            gm = fmaxf(gm, gmax[(size_t)q * SC + g * gsz + j]);
        tv = fminf(tv, gm);
    }
    thrm[q] = tv - MARGIN;
}

// ---------------------------------------------------------------------------
// Exact per-query top-32 over slotted candidates (+overflow): 4-pass radix
// select + collect + tie-breaking tournament (score desc, idx asc).
// out: [0..B*K) = indices (as float); [B*K..2BK) = scores.
// ---------------------------------------------------------------------------
__global__ __launch_bounds__(256) void select_topk(
    const float* __restrict__ cs, const int* __restrict__ ci,
    const int* __restrict__ cnt2,
    const int* __restrict__ ocnt, const int* __restrict__ oq,
    const int* __restrict__ og, const float* __restrict__ osv,
    float* __restrict__ out, int CBLK)
{
    __shared__ int   cntRow[2048];
    __shared__ int   hist[256];
    __shared__ int   hscan[256];
    __shared__ float Ls[256];
    __shared__ int   Li[256];
    __shared__ int   lcnt, nTotS, bS, gtS;
    __shared__ float wrs[4]; __shared__ int wri[4], wrslot[4];

    const int q = blockIdx.x;
    const int t = threadIdx.x;
    const size_t qbase = (size_t)q * CBLK * SLOTS;
    const size_t cbase = (size_t)q * CBLK;
    const int CC = CBLK < 2048 ? CBLK : 2048;
    const int novf0 = *ocnt;
    const int novf = novf0 < OCAP ? novf0 : OCAP;
    const int nslots = CBLK * SLOTS;

    for (int i = t; i < CC; i += 256) cntRow[i] = cnt2[cbase + i];
    if (t == 0) nTotS = 0;
    __syncthreads();
    {
        int part = 0;
        for (int i = t; i < CBLK; i += 256)
            part += (i < 2048) ? cntRow[i] : cnt2[cbase + i];
        for (int i = t; i < novf; i += 256)
            if (oq[i] == q) part++;
        atomicAdd(&nTotS, part);
    }
    __syncthreads();
    const int nTot = nTotS;

    unsigned prefix = 0, pmask = 0;
    int kneed = KTOP;

    if (nTot > KTOP) {
        for (int pass = 0; pass < 4; ++pass) {
            const int shift = 24 - pass * 8;
            hist[t] = 0;
            __syncthreads();
            for (int i = t; i < nslots; i += 256) {
                const int b = i >> 3, sl = i & 7;
                const int cb = (b < 2048) ? cntRow[b] : cnt2[cbase + b];
                if (sl < cb) {
                    unsigned k = fkey(cs[qbase + i]);
                    if ((k & pmask) == prefix)
                        atomicAdd(&hist[(k >> shift) & 255], 1);
                }
            }
            for (int i = t; i < novf; i += 256) {
                if (oq[i] == q) {
                    unsigned k = fkey(osv[i]);
                    if ((k & pmask) == prefix)
                        atomicAdd(&hist[(k >> shift) & 255], 1);
                }
            }
            __syncthreads();
            int* src = hist; int* dst = hscan;
            for (int off = 1; off < 256; off <<= 1) {
                int v = src[t] + ((t + off) < 256 ? src[t + off] : 0);
                __syncthreads();
                dst[t] = v;
                __syncthreads();
                int* tmp = src; src = dst; dst = tmp;
            }
            if (src[t] >= kneed && (t == 255 || src[t + 1] < kneed)) {
                bS = t;
                gtS = (t == 255) ? 0 : src[t + 1];
            }
            __syncthreads();
            const int b = bS;
            kneed -= gtS;
            prefix |= ((unsigned)b) << shift;
            pmask  |= 0xFFu << shift;
            __syncthreads();
        }
    }

    if (t == 0) lcnt = 0;
    __syncthreads();
    const unsigned T = (nTot > KTOP) ? prefix : 0u;
    for (int i = t; i < nslots; i += 256) {
        const int b = i >> 3, sl = i & 7;
        const int cb = (b < 2048) ? cntRow[b] : cnt2[cbase + b];
        if (sl < cb) {
            float s = cs[qbase + i];
            if (fkey(s) >= T) {
                int p = atomicAdd(&lcnt, 1);
                if (p < 256) { Ls[p] = s; Li[p] = ci[qbase + i]; }
            }
        }
    }
    for (int i = t; i < novf; i += 256) {
        if (oq[i] == q) {
            float s = osv[i];
            if (fkey(s) >= T) {
                int p = atomicAdd(&lcnt, 1);
                if (p < 256) { Ls[p] = s; Li[p] = og[i]; }
            }
        }
    }
    __syncthreads();
    const int M = lcnt < 256 ? lcnt : 256;

    const int w = t >> 6, lane = t & 63;
    for (int r = 0; r < KTOP; ++r) {
        float bv = (t < M) ? Ls[t] : NEG_INF;
        int   bi = (t < M) ? Li[t] : 0x7fffffff;
        int   bslot = t;
        #pragma unroll
        for (int off = 32; off > 0; off >>= 1) {
            float ov = __shfl_xor(bv, off);
            int   oi = __shfl_xor(bi, off);
            int   osl = __shfl_xor(bslot, off);
            if (pri_gt(ov, oi, bv, bi)) { bv = ov; bi = oi; bslot = osl; }
        }
        if (lane == 0) { wrs[w] = bv; wri[w] = bi; wrslot[w] = bslot; }
        __syncthreads();
        if (t == 0) {
            float fv = wrs[0]; int fi = wri[0]; int fs = wrslot[0];
            #pragma unroll
            for (int ww = 1; ww < 4; ++ww)
                if (pri_gt(wrs[ww], wri[ww], fv, fi)) {
                    fv = wrs[ww]; fi = wri[ww]; fs = wrslot[ww];
                }
            out[q * KTOP + r]                     = (float)fi;
            out[(size_t)BQ * KTOP + q * KTOP + r] = fv;
            Ls[fs] = NEG_INF; Li[fs] = 0x7fffffff;
        }
        __syncthreads();
    }
}

// ---------------------------------------------------------------------------
extern "C" void kernel_launch(void* const* d_in, const int* in_sizes, int n_in,
                              void* d_out, int out_size, void* d_ws, size_t ws_size,
                              hipStream_t stream)
{
    const float* Qf   = (const float*)d_in[0];
    const float* G    = (const float*)d_in[1];
    const int*   mask = (const int*)d_in[2];
    const int Ntot = in_sizes[1] / DK;                 // 200000

    const int CBLK = (Ntot + ITEMS - 1) / ITEMS;       // 1563
    int SC = SCN;                                      // sample chunks
    if (SC > CBLK) SC = (CBLK / 32) * 32;              // keep 32 groups
    if (SC < 32) SC = 32;

    // ws layout (bytes)
    char* w = (char*)d_ws;
    int*            ocnt = (int*)(w + 0);              // [0,4096) control
    float*          thrm = (float*)(w + 4096);         // 512 B
    float*          gmax = (float*)(w + 8192);         // 128*SC*4
    size_t off = 8192 + (size_t)BQ * SC * 4;
    off = (off + 255) & ~(size_t)255;
    unsigned short* Qb = (unsigned short*)(w + off);   // 128*192*2
    off += (size_t)BQ * DK * 2; off = (off + 255) & ~(size_t)255;
    int*   cnt2 = (int*)(w + off);                     // 128*CBLK*4
    off += (size_t)BQ * CBLK * 4; off = (off + 255) & ~(size_t)255;
    float* cs   = (float*)(w + off);                   // 128*CBLK*SLOTS*4
    off += (size_t)BQ * CBLK * SLOTS * 4;
    int*   ci   = (int*)(w + off);
    off += (size_t)BQ * CBLK * SLOTS * 4;
    int*   oqv  = (int*)(w + off);   off += (size_t)OCAP * 4;
    int*   ogv  = (int*)(w + off);   off += (size_t)OCAP * 4;
    float* osv  = (float*)(w + off);

    (void)hipMemsetAsync(w, 0, 4096, stream);
    qprep<<<dim3((BQ * DK + 255) / 256), dim3(256), 0, stream>>>(Qf, Qb);
    mfma_score<<<dim3(SC), dim3(256), 0, stream>>>(
        Qf, Qb, G, mask, thrm, gmax, cnt2, cs, ci, ocnt, oqv, ogv, osv,
        Ntot, CBLK, SC, 0);
    thresh_reduce<<<dim3(1), dim3(BQ), 0, stream>>>(gmax, thrm, SC);
    mfma_score<<<dim3(CBLK), dim3(256), 0, stream>>>(
        Qf, Qb, G, mask, thrm, gmax, cnt2, cs, ci, ocnt, oqv, ogv, osv,
        Ntot, CBLK, SC, 1);
    select_topk<<<dim3(BQ), dim3(256), 0, stream>>>(
        cs, ci, cnt2, ocnt, oqv, ogv, osv, (float*)d_out, CBLK);
}